// Round 1
// 366.558 us; speedup vs baseline: 1.1137x; 1.1137x over previous
//
#include <hip/hip_runtime.h>
#include <hip/hip_bf16.h>
#include <math.h>

#define NPTS  8192
#define DIM   512
#define KNNK  15
#define NCAND 18      // approx candidates kept for exact refine (30+ sigma margin)
#define NPAIR 105
#define CINF  3.0e38f

// knn tiling
#define NI      128
#define NJSPLIT 8
#define NJ      (NPTS/NJSPLIT)   // 1024
#define JS      128
#define NSUB    (NJ/JS)          // 8
#define BK      32
#define NSC     8                // superchunks of 2*BK=64 over DIM=512
#define DSTRIDE 132              // 16B-aligned rows; b128 scan reads 2-way (free)

// knn LDS byte map: sdist[128][132] (67584 B) aliases the two 32KB staging bufs
#define BUF0_OFF   0
#define BUF1_OFF   32768
#define SQJ_OFF    67584
#define TLS_OFF    71680
#define KNN_LDS    72704

typedef __attribute__((ext_vector_type(8))) short short8;
typedef __attribute__((ext_vector_type(4))) float f32x4;

static __device__ __forceinline__ float wave_sum_f(float v) {
#pragma unroll
  for (int m = 32; m > 0; m >>= 1) v += __shfl_xor(v, m, 64);
  return v;
}

static __device__ __forceinline__ void load_lds16(const void* g, void* l) {
  __builtin_amdgcn_global_load_lds(
      (const __attribute__((address_space(1))) void*)g,
      (__attribute__((address_space(3))) void*)l, 16, 0, 0);
}

static __device__ __forceinline__ void bf16split(float x, short& h, short& l) {
  __hip_bfloat16 hb = __float2bfloat16(x);
  const float hf = __bfloat162float(hb);
  __hip_bfloat16 lb = __float2bfloat16(x - hf);
  h = *(short*)&hb;
  l = *(short*)&lb;
}

// ---------------------------------------------------------------- prep
// EA = bf16(-sqrt2 * E), EB = bf16(+sqrt2 * E): screen MFMA then yields
// -2*dot directly so acc can be initialized with sqn_j (no writeback fma).
__global__ __launch_bounds__(256) void prep_kernel(
    const float* __restrict__ E, float* __restrict__ sqn,
    ushort* __restrict__ EA, ushort* __restrict__ EB) {
  const int row  = blockIdx.x * 4 + (threadIdx.x >> 6);
  const int lane = threadIdx.x & 63;
  const float SR2 = 1.4142135623730951f;
  float s = 0.f;
#pragma unroll
  for (int c = 0; c < 8; ++c) {
    const int d0 = lane + 64 * c;
    const float x = E[(size_t)row * DIM + d0];
    s = fmaf(x, x, s);
    __hip_bfloat16 ha = __float2bfloat16(-SR2 * x);
    __hip_bfloat16 hb = __float2bfloat16( SR2 * x);
    EA[(size_t)row * DIM + d0] = *(ushort*)&ha;
    EB[(size_t)row * DIM + d0] = *(ushort*)&hb;
  }
  s = wave_sum_f(s);
  if (lane == 0) sqn[row] = s;
}

// ---------------------------------------------------------------- knn
// HI-ONLY SCREEN: distances at bf16 precision (err std ~0.1 on dist^2 vs
// order-stat gap ~1.1) -- exact fp32 refine happens in sig_kernel on the
// merged top-NCAND. 1 MFMA per fragment (was 3), 8 ds_reads per chunk
// (was 16), staging bytes halved. BK=64 superchunks (two [128][32] tiles
// per side, conflict-balanced layout) halve barrier count.
__global__ __launch_bounds__(256, 2) void knn_kernel(
    const ushort* __restrict__ EA, const ushort* __restrict__ EB,
    const float* __restrict__ sqn,
    float* __restrict__ cd, int* __restrict__ ci) {
  __shared__ __align__(16) char sm[KNN_LDS];
  float* sdist = (float*)sm;
  float* sqjs  = (float*)(sm + SQJ_OFF);
  float* tls   = (float*)(sm + TLS_OFF);

  const int tid = threadIdx.x;
  const int w   = tid >> 6;
  const int L   = tid & 63;
  const int wr  = w >> 1;
  const int wc  = w & 1;
  const int i0  = blockIdx.x * NI;     // i-tile (XCD-affine)
  const int jsplit = blockIdx.y;
  const int j0  = jsplit * NJ;

  ((float4*)sqjs)[tid] = ((const float4*)(sqn + j0))[tid];
  tls[tid] = CINF;

  // staging: wave w owns one 8KB tile per superchunk:
  //   w0: A chunk-even, w1: A chunk-odd, w2: B chunk-even, w3: B chunk-odd
  const ushort* gsrc = (w < 2) ? EA : EB;
  const int lrow = L >> 2;
  const int lk8  = (L & 3) * 8;

  const int myrow = tid >> 1;
  const int h     = tid & 1;
  const int gi    = i0 + myrow;

  float td[15]; int tj[15];
#pragma unroll
  for (int p = 0; p < 15; ++p) { td[p] = CINF; tj[p] = -1; }

  __syncthreads();

  for (int js = 0; js < NSUB; ++js) {
    const int jrow0 = j0 + js * JS;
    const int trow0 = (w < 2) ? i0 : jrow0;
    // fold chunk parity (w&1)*BK into the base; superchunk t adds t*64
    const ushort* gbase = gsrc + (size_t)(trow0 + lrow) * DIM + lk8 + wc * BK;

    // acc init = sqn_j (MFMA accumulates -2*dot on top)
    float sqjv[4];
#pragma unroll
    for (int fc = 0; fc < 4; ++fc)
      sqjv[fc] = sqjs[js * 128 + wc * 64 + fc * 16 + (L & 15)];
    f32x4 acc[4][4];
#pragma unroll
    for (int fr = 0; fr < 4; ++fr)
#pragma unroll
      for (int fc = 0; fc < 4; ++fc)
#pragma unroll
        for (int r = 0; r < 4; ++r) acc[fr][fc][r] = sqjv[fc];

    // prologue: stage superchunk 0 into buf0
    {
      char* lp = sm + BUF0_OFF + w * 8192;
#pragma unroll
      for (int s = 0; s < 8; ++s)
        load_lds16(gbase + (size_t)s * 16 * DIM, lp + s * 1024);
    }
    __syncthreads();

#pragma unroll 2
    for (int t = 0; t < NSC; ++t) {
      const int cb  = (t & 1) ? BUF1_OFF : BUF0_OFF;
      const int nbo = (t & 1) ? BUF0_OFF : BUF1_OFF;
      if (t < NSC - 1) {
        char* lp = sm + nbo + w * 8192;
        const ushort* gp = gbase + (t + 1) * 64;
#pragma unroll
        for (int s = 0; s < 8; ++s)
          load_lds16(gp + (size_t)s * 16 * DIM, lp + s * 1024);
      }

      const ushort* sA0 = (const ushort*)(sm + cb);
      const ushort* sA1 = (const ushort*)(sm + cb + 8192);
      const ushort* sB0 = (const ushort*)(sm + cb + 16384);
      const ushort* sB1 = (const ushort*)(sm + cb + 24576);

      short8 a0[4], a1[4], b0[4], b1[4];
      const int q16 = (L >> 4) * 8;
#pragma unroll
      for (int f = 0; f < 4; ++f) {
        const int ra = (wr * 64 + f * 16 + (L & 15)) * BK + q16;
        const int rb = (wc * 64 + f * 16 + (L & 15)) * BK + q16;
        a0[f] = *(const short8*)&sA0[ra];
        a1[f] = *(const short8*)&sA1[ra];
        b0[f] = *(const short8*)&sB0[rb];
        b1[f] = *(const short8*)&sB1[rb];
      }
#pragma unroll
      for (int fr = 0; fr < 4; ++fr)
#pragma unroll
        for (int fc = 0; fc < 4; ++fc) {
          acc[fr][fc] = __builtin_amdgcn_mfma_f32_16x16x32_bf16(a0[fr], b0[fc], acc[fr][fc], 0, 0, 0);
          acc[fr][fc] = __builtin_amdgcn_mfma_f32_16x16x32_bf16(a1[fr], b1[fc], acc[fr][fc], 0, 0, 0);
        }
      __syncthreads();   // drains next-superchunk staging; orders buffer reuse
    }

    // ---- screen distances: acc already = sqj - 2*dot~; pure store
#pragma unroll
    for (int fr = 0; fr < 4; ++fr)
#pragma unroll
      for (int fc = 0; fc < 4; ++fc)
#pragma unroll
        for (int r = 0; r < 4; ++r) {
          const int row_l = wr * 64 + fr * 16 + (L >> 4) * 4 + r;
          const int col_l = wc * 64 + fc * 16 + (L & 15);
          sdist[row_l * DSTRIDE + col_l] = acc[fr][fc][r];
        }
    __syncthreads();

    // ---- tau + self-poke + batch-4 scan over contiguous half-row
    const float tau = fminf(tls[myrow * 2], tls[myrow * 2 + 1]);
    const int selfc = gi - jrow0;
    if (selfc >= 0 && selfc < JS && h == (selfc >> 6))
      sdist[myrow * DSTRIDE + selfc] = CINF;

    const float* rp = sdist + myrow * DSTRIDE + 64 * h;
    float guard = fminf(tau, td[14]);
    const int jb = jrow0 + 64 * h;
#pragma unroll 2
    for (int q = 0; q < 16; ++q) {
      const float4 dv = *(const float4*)&rp[4 * q];
      const float mn = fminf(fminf(dv.x, dv.y), fminf(dv.z, dv.w));
      if (mn < guard) {
        const float c4[4] = {dv.x, dv.y, dv.z, dv.w};
#pragma unroll
        for (int t = 0; t < 4; ++t) {
          const float dd = c4[t];
          if (dd < guard) {
            float cdv = dd; int cjv = jb + 4 * q + t;
#pragma unroll
            for (int p = 0; p < 15; ++p) {
              const bool lt = cdv < td[p];
              const float vmin = lt ? cdv : td[p];
              const float vmax = lt ? td[p] : cdv;
              const int imin = lt ? cjv : tj[p];
              const int imax = lt ? tj[p] : cjv;
              td[p] = vmin; tj[p] = imin; cdv = vmax; cjv = imax;
            }
            guard = fminf(tau, td[14]);
          }
        }
      }
    }
    tls[myrow * 2 + h] = td[14];
    __syncthreads();
  }

  // ---- pair-merge -> top-15 per (row, split); raw screen values out
  float* md  = sdist;
  int*   mi_ = (int*)(sm + 16384);
#pragma unroll
  for (int p = 0; p < 15; ++p) {
    md[(myrow * 2 + h) * 15 + p]  = td[p];
    mi_[(myrow * 2 + h) * 15 + p] = tj[p];
  }
  __syncthreads();
  if (h == 0) {
    const float* da = &md[(myrow * 2 + 0) * 15];
    const float* db = &md[(myrow * 2 + 1) * 15];
    const int*   ia = &mi_[(myrow * 2 + 0) * 15];
    const int*   ib = &mi_[(myrow * 2 + 1) * 15];
    int pa = 0, pb = 0;
    const size_t base = ((size_t)gi * NJSPLIT + jsplit) * KNNK;
    for (int s2 = 0; s2 < KNNK; ++s2) {
      const float va = da[pa], vb = db[pb];
      float v; int ix;
      if (va <= vb) { v = va; ix = ia[pa]; ++pa; }
      else          { v = vb; ix = ib[pb]; ++pb; }
      cd[base + s2] = v;       // approx screen value; exact refine in sig
      ci[base + s2] = ix;
    }
  }
}

// ---------------------------------------------------------------- sig
// One wave per point. Merge 8 lists -> approx top-NCAND -> EXACT fp32
// refine (sum of squared diffs) -> exact top-15 -> curvature -> gram via
// split-bf16 MFMA -> shuffle bitonic-128 -> per-wave partial (no atomics).
__global__ __launch_bounds__(256) void sig_kernel(
    const float* __restrict__ E, const float* __restrict__ cd,
    const int* __restrict__ ci, const float* __restrict__ refc,
    const float* __restrict__ refa, float2* __restrict__ pacc) {
  __shared__ float gsm[4][292];   // per-wave: gram 16x17 (=272) + inv[16]

  const int tid = threadIdx.x;
  const int wid = tid >> 6;
  const int L   = tid & 63;
  const int i   = blockIdx.x * 4 + wid;

  // ---- merge 8 sorted 15-lists -> approx top-NCAND ids (lane c holds cand c)
  const size_t mbase = (size_t)i * (NJSPLIT * KNNK);
  float v0 = (L < 120)      ? cd[mbase + L]      : CINF;
  float v1 = (L + 64 < 120) ? cd[mbase + L + 64] : CINF;
  int   j0v = (L < 120)      ? ci[mbase + L]      : -1;
  int   j1v = (L + 64 < 120) ? ci[mbase + L + 64] : -1;
  int cand_nb = i;
  for (int sel = 0; sel < NCAND; ++sel) {
    float v; int idx, slot;
    if (v1 < v0) { v = v1; idx = j1v; slot = (L << 1) | 1; }
    else         { v = v0; idx = j0v; slot = (L << 1); }
#pragma unroll
    for (int off = 32; off > 0; off >>= 1) {
      const float ov = __shfl_down(v, off, 64);
      const int   oi = __shfl_down(idx, off, 64);
      const int   os = __shfl_down(slot, off, 64);
      if (ov < v) { v = ov; idx = oi; slot = os; }
    }
    const int imin = __shfl(idx, 0, 64);
    const int smin = __shfl(slot, 0, 64);
    if (L == sel) cand_nb = imin;
    if (L == (smin >> 1)) { if (smin & 1) v1 = CINF; else v0 = CINF; }
  }

  // ---- exact refine: fp32 squared distance for each candidate
  const float4* ei4 = (const float4*)(E + (size_t)i * DIM);
  const float4 e0 = ei4[2 * L];
  const float4 e1 = ei4[2 * L + 1];
  float csq = CINF;
#pragma unroll 2
  for (int c = 0; c < NCAND; ++c) {
    const int row = __shfl(cand_nb, c, 64);
    const float4* r4 = (const float4*)(E + (size_t)row * DIM);
    const float4 a0 = r4[2 * L];
    const float4 a1 = r4[2 * L + 1];
    const float d0 = a0.x - e0.x, d1 = a0.y - e0.y;
    const float d2 = a0.z - e0.z, d3 = a0.w - e0.w;
    const float d4 = a1.x - e1.x, d5 = a1.y - e1.y;
    const float d6 = a1.z - e1.z, d7 = a1.w - e1.w;
    float s8 = d0 * d0;
    s8 = fmaf(d1, d1, s8); s8 = fmaf(d2, d2, s8); s8 = fmaf(d3, d3, s8);
    s8 = fmaf(d4, d4, s8); s8 = fmaf(d5, d5, s8); s8 = fmaf(d6, d6, s8);
    s8 = fmaf(d7, d7, s8);
    const float sq = wave_sum_f(s8);
    if (L == c) csq = sq;
  }

  // ---- exact top-15 (ascending); lane-group (L&15)==sel captures rank sel
  float myd = 0.f; int mynb = i;
  for (int sel = 0; sel < KNNK; ++sel) {
    float v = csq; int who = L;
#pragma unroll
    for (int off = 32; off > 0; off >>= 1) {
      const float ov = __shfl_down(v, off, 64);
      const int   ow = __shfl_down(who, off, 64);
      if (ov < v) { v = ov; who = ow; }
    }
    const float vmin  = __shfl(v, 0, 64);
    const int   wmin  = __shfl(who, 0, 64);
    const int   nbmin = __shfl(cand_nb, wmin, 64);
    if ((L & 15) == sel) { myd = sqrtf(fmaxf(vmin, 1e-12f)); mynb = nbmin; }
    if (L == wmin) csq = CINF;
  }

  // ---- curvature (lanes 0..14 hold d_0..d_14)
  float curvs;
  {
    float dd = (L < KNNK) ? myd : 0.f;
    float tot = wave_sum_f(dd);
    float mean_d = tot / (float)KNNK + 1e-8f;
    float diff = (L < KNNK) ? (dd / mean_d - refc[i * KNNK + L]) : 0.f;
    curvs = wave_sum_f(diff * diff);
  }

  // ---- gram of raw neighbor differences (row = L&15; row 15 = self -> zero)
  const float4* nb4 = (const float4*)(E + (size_t)mynb * DIM);
  const int qo = (L >> 4) * 2;   // float4 index of this lane's 8-elem k-slice

  f32x4 gH, gX;
#pragma unroll
  for (int r = 0; r < 4; ++r) { gH[r] = 0.f; gX[r] = 0.f; }

#pragma unroll
  for (int c = 0; c < 16; ++c) {
    const float4 f0 = nb4[qo + c * 8];
    const float4 f1 = nb4[qo + 1 + c * 8];
    const float4 g0 = ei4[qo + c * 8];
    const float4 g1 = ei4[qo + 1 + c * 8];
    float v[8];
    v[0] = f0.x - g0.x; v[1] = f0.y - g0.y; v[2] = f0.z - g0.z; v[3] = f0.w - g0.w;
    v[4] = f1.x - g1.x; v[5] = f1.y - g1.y; v[6] = f1.z - g1.z; v[7] = f1.w - g1.w;
    short8 ah, al;
#pragma unroll
    for (int q = 0; q < 8; ++q) {
      short hh, ll;
      bf16split(v[q], hh, ll);
      ah[q] = hh; al[q] = ll;
    }
    gH = __builtin_amdgcn_mfma_f32_16x16x32_bf16(ah, ah, gH, 0, 0, 0);
    gX = __builtin_amdgcn_mfma_f32_16x16x32_bf16(ah, al, gX, 0, 0, 0);
    gX = __builtin_amdgcn_mfma_f32_16x16x32_bf16(al, ah, gX, 0, 0, 0);
  }

  // write gram to per-wave LDS: C/D layout col=L&15, row=(L>>4)*4+q
#pragma unroll
  for (int q = 0; q < 4; ++q)
    gsm[wid][((L >> 4) * 4 + q) * 17 + (L & 15)] = gH[q] + gX[q];
  asm volatile("s_waitcnt lgkmcnt(0)" ::: "memory");

  if (L < 16) {
    const float dv = gsm[wid][L * 17 + L];
    const float nrm = sqrtf(fmaxf(dv, 0.f));
    gsm[wid][272 + L] = 1.0f / fmaxf(nrm, 1e-8f);
  }
  asm volatile("s_waitcnt lgkmcnt(0)" ::: "memory");

  // cosines for pairs p = L and p+64
  float c0 = CINF, c1 = CINF;
#pragma unroll
  for (int s = 0; s < 2; ++s) {
    const int p = L + 64 * s;
    if (p < NPAIR) {
      int a = 0, rem = p, cnt = 14;
      while (rem >= cnt) { rem -= cnt; --cnt; ++a; }
      const int b = a + 1 + rem;
      const float cv = gsm[wid][a * 17 + b] * gsm[wid][272 + a] * gsm[wid][272 + b];
      if (s == 0) c0 = cv; else c1 = cv;
    }
  }

  // shuffle bitonic sort of 128 elems (2 per lane), ascending
#pragma unroll
  for (int k = 2; k <= 128; k <<= 1) {
#pragma unroll
    for (int j = k >> 1; j >= 1; j >>= 1) {
      const bool dir = ((L & (k >> 1)) == 0);
      if (j == 1) {
        const float lo = fminf(c0, c1), hi = fmaxf(c0, c1);
        c0 = dir ? lo : hi;
        c1 = dir ? hi : lo;
      } else {
        const int m = j >> 1;
        const float o0 = __shfl_xor(c0, m, 64);
        const float o1 = __shfl_xor(c1, m, 64);
        const bool lower = ((L & m) == 0);
        c0 = (lower == dir) ? fminf(c0, o0) : fmaxf(c0, o0);
        c1 = (lower == dir) ? fminf(c1, o1) : fmaxf(c1, o1);
      }
    }
  }

  // angular loss vs sorted reference (rank 2L, 2L+1)
  float part = 0.f;
  {
    const int r0 = 2 * L, r1 = 2 * L + 1;
    if (r0 < NPAIR) { const float dd = c0 - refa[(size_t)i * NPAIR + r0]; part += dd * dd; }
    if (r1 < NPAIR) { const float dd = c1 - refa[(size_t)i * NPAIR + r1]; part += dd * dd; }
  }
  part = wave_sum_f(part);
  if (L == 0) pacc[i] = make_float2(curvs, part);   // non-atomic per-wave slot
}

// ---------------------------------------------------------------- fin
__global__ __launch_bounds__(256) void fin_kernel(
    const float2* __restrict__ pacc, float* __restrict__ out) {
  __shared__ double redc[4], reda[4];
  const int tid = threadIdx.x;
  const int wid = tid >> 6;
  const int L   = tid & 63;
  double sc = 0.0, sa = 0.0;
#pragma unroll
  for (int q = 0; q < 32; ++q) {
    const float2 p = pacc[tid + 256 * q];
    sc += (double)p.x;
    sa += (double)p.y;
  }
#pragma unroll
  for (int m = 32; m > 0; m >>= 1) {
    sc += __shfl_xor(sc, m, 64);
    sa += __shfl_xor(sa, m, 64);
  }
  if (L == 0) { redc[wid] = sc; reda[wid] = sa; }
  __syncthreads();
  if (tid == 0) {
    const double curv = (redc[0] + redc[1] + redc[2] + redc[3]) /
                        ((double)NPTS * (double)KNNK);
    const double ang  = (reda[0] + reda[1] + reda[2] + reda[3]) /
                        ((double)NPTS * (double)NPAIR);
    out[0] = (float)(0.3 * curv + 0.7 * ang);
  }
}

// ---------------------------------------------------------------- launch
extern "C" void kernel_launch(void* const* d_in, const int* in_sizes, int n_in,
                              void* d_out, int out_size, void* d_ws,
                              size_t ws_size, hipStream_t stream) {
  const float* E    = (const float*)d_in[0];
  const float* refc = (const float*)d_in[1];
  const float* refa = (const float*)d_in[2];
  float* out = (float*)d_out;

  char* ws = (char*)d_ws;
  float*  sqn  = (float*)(ws + 1024);
  float2* pacc = (float2*)(ws + 65536);
  ushort* EA   = (ushort*)(ws + 1048576);
  ushort* EB   = (ushort*)(ws + 9437184);
  float*  cd   = (float*)(ws + 17825792);
  int*    ci   = (int*)(ws + 21757952);

  prep_kernel<<<NPTS / 4, 256, 0, stream>>>(E, sqn, EA, EB);
  knn_kernel<<<dim3(NPTS / NI, NJSPLIT), 256, 0, stream>>>(EA, EB, sqn, cd, ci);
  sig_kernel<<<NPTS / 4, 256, 0, stream>>>(E, cd, ci, refc, refa, pacc);
  fin_kernel<<<1, 256, 0, stream>>>(pacc, out);
}